// Round 12
// baseline (264.946 us; speedup 1.0000x reference)
//
#include <hip/hip_runtime.h>
#include <cstdint>

// ---------- types & helpers ----------
typedef unsigned short u16;
typedef __bf16 bf16x8 __attribute__((ext_vector_type(8)));
typedef float  f32x4  __attribute__((ext_vector_type(4)));

struct alignas(16) F4 { float v[4]; };
struct alignas(8)  U4 { u16 v[4]; };
struct alignas(16) U8 { u16 v[8]; };

__device__ __forceinline__ u16 f2bf(float f) {
    union { float f; unsigned int u; } x; x.f = f;
    unsigned int r = x.u + 0x7fffu + ((x.u >> 16) & 1u);   // RNE
    return (u16)(r >> 16);
}
__device__ __forceinline__ float bf2f(u16 u) {
    union { unsigned int u; float f; } x; x.u = ((unsigned int)u) << 16;
    return x.f;
}
__device__ __forceinline__ f32x4 mfma16(bf16x8 a, bf16x8 b, f32x4 c) {
    return __builtin_amdgcn_mfma_f32_16x16x32_bf16(a, b, c, 0, 0, 0);
}
__device__ __forceinline__ bf16x8 ldf(const u16* p) { return *(const bf16x8*)p; }
// async global->LDS, 16B per lane, dest = wave-uniform base + lane*16
__device__ __forceinline__ void gload_lds16(const void* g, void* l) {
    auto* gp = reinterpret_cast<const __attribute__((address_space(1))) unsigned int*>(
        reinterpret_cast<uintptr_t>(g));
    auto* lp = reinterpret_cast<__attribute__((address_space(3))) unsigned int*>(
        reinterpret_cast<uintptr_t>(l));
    __builtin_amdgcn_global_load_lds(gp, lp, 16, 0, 0);
}

// ---------- ALL weight casts in one kernel ----------
__global__ __launch_bounds__(256) void cast_all_k(const float* __restrict__ qkvw,
                                                  const float* __restrict__ attow,
                                                  const float* __restrict__ mlpow,
                                                  const float* __restrict__ wi,
                                                  const float* __restrict__ wg,
                                                  u16* __restrict__ wq,
                                                  u16* __restrict__ wo,
                                                  u16* __restrict__ wm,
                                                  u16* __restrict__ wig) {
    constexpr int N1 = 3 * 1024 * 1024 / 8;            // wq units-of-8
    constexpr int N2 = N1 + 1024 * 1024 / 8;           // +wo
    constexpr int N3 = N2 + 1024 * 4096 / 8;           // +wm
    const int i = blockIdx.x * 256 + threadIdx.x;
    const float* src; u16* dst;
    if (i < N1)      { src = qkvw  + (size_t)i * 8;        dst = wq + (size_t)i * 8; }
    else if (i < N2) { const int j = i - N1; src = attow + (size_t)j * 8; dst = wo + (size_t)j * 8; }
    else if (i < N3) { const int j = i - N2; src = mlpow + (size_t)j * 8; dst = wm + (size_t)j * 8; }
    else {
        const int j = i - N3;
        const int w = j >> 7, c8 = (j & 127) * 8;
        const int f = ((w >> 6) << 5) | (w & 31);
        src = ((w & 32) ? wg : wi) + (size_t)f * 1024 + c8;
        dst = wig + (size_t)w * 1024 + c8;
    }
    F4 a = *(const F4*)src;
    F4 b = *(const F4*)(src + 4);
    U8 o;
    #pragma unroll
    for (int j = 0; j < 4; ++j) { o.v[j] = f2bf(a.v[j]); o.v[4 + j] = f2bf(b.v[j]); }
    *(U8*)dst = o;
}

// ---------- LayerNorm (C=1024), f32 in -> bf16 out ----------
__global__ __launch_bounds__(256) void ln_fwd_k(const float* __restrict__ x,
                                                const float* __restrict__ w,
                                                const float* __restrict__ b,
                                                u16* __restrict__ h) {
    const int row = blockIdx.x, tid = threadIdx.x;
    const float* xr = x + (size_t)row * 1024;
    F4 v = *(const F4*)(xr + tid * 4);
    float s  = v.v[0] + v.v[1] + v.v[2] + v.v[3];
    float ss = v.v[0]*v.v[0] + v.v[1]*v.v[1] + v.v[2]*v.v[2] + v.v[3]*v.v[3];
    #pragma unroll
    for (int o = 32; o > 0; o >>= 1) { s += __shfl_down(s, o); ss += __shfl_down(ss, o); }
    __shared__ float red[8];
    const int wave = tid >> 6, lane = tid & 63;
    if (lane == 0) { red[wave] = s; red[4 + wave] = ss; }
    __syncthreads();
    s  = red[0] + red[1] + red[2] + red[3];
    ss = red[4] + red[5] + red[6] + red[7];
    const float mu   = s * (1.0f / 1024.0f);
    const float var  = ss * (1.0f / 1024.0f) - mu * mu;
    const float rstd = rsqrtf(var + 1e-5f);
    U4 o;
    #pragma unroll
    for (int j = 0; j < 4; ++j)
        o.v[j] = f2bf((v.v[j] - mu) * rstd * w[tid * 4 + j] + b[tid * 4 + j]);
    *(U4*)(h + (size_t)row * 1024 + tid * 4) = o;
}

// ---------- fused residual + LN2: x1 = x + p0 + p1 (bf16 planes); h2 = LN(x1) ----------
__global__ __launch_bounds__(256) void ln_resid_k(const float* __restrict__ x,
                                                  const u16* __restrict__ p,
                                                  const float* __restrict__ w,
                                                  const float* __restrict__ b,
                                                  float* __restrict__ x1,
                                                  u16* __restrict__ h,
                                                  int planeEls) {
    const int row = blockIdx.x, tid = threadIdx.x;
    const size_t base = (size_t)row * 1024 + tid * 4;
    F4 xv = *(const F4*)(x + base);
    U4 q0 = *(const U4*)(p + base);
    U4 q1 = *(const U4*)(p + (size_t)planeEls + base);
    F4 sv;
    #pragma unroll
    for (int j = 0; j < 4; ++j) sv.v[j] = xv.v[j] + bf2f(q0.v[j]) + bf2f(q1.v[j]);
    *(F4*)(x1 + base) = sv;
    float s  = sv.v[0] + sv.v[1] + sv.v[2] + sv.v[3];
    float ss = sv.v[0]*sv.v[0] + sv.v[1]*sv.v[1] + sv.v[2]*sv.v[2] + sv.v[3]*sv.v[3];
    #pragma unroll
    for (int o = 32; o > 0; o >>= 1) { s += __shfl_down(s, o); ss += __shfl_down(ss, o); }
    __shared__ float red[8];
    const int wave = tid >> 6, lane = tid & 63;
    if (lane == 0) { red[wave] = s; red[4 + wave] = ss; }
    __syncthreads();
    s  = red[0] + red[1] + red[2] + red[3];
    ss = red[4] + red[5] + red[6] + red[7];
    const float mu   = s * (1.0f / 1024.0f);
    const float var  = ss * (1.0f / 1024.0f) - mu * mu;
    const float rstd = rsqrtf(var + 1e-5f);
    U4 o;
    #pragma unroll
    for (int j = 0; j < 4; ++j)
        o.v[j] = f2bf((sv.v[j] - mu) * rstd * w[tid * 4 + j] + b[tid * 4 + j]);
    *(U4*)(h + base) = o;
}

// ---------- combined qk + vt GEMM (one dispatch, 768 blocks) ----------
__global__ __launch_bounds__(256) void gemm_qkvt_k(const u16* __restrict__ h1,
                                                   const u16* __restrict__ wq,
                                                   u16* __restrict__ qk_b,
                                                   u16* __restrict__ vt_b) {
    __shared__ alignas(16) u16 Alds[128 * 32];
    __shared__ alignas(16) u16 Blds[128 * 32];
    const int tid  = threadIdx.x;
    const int lane = tid & 63, wave = tid >> 6;
    const int wr = wave >> 1, wc = wave & 1;
    const int r16 = lane & 15, g16 = lane >> 4;

    const u16* A; const u16* Bm; u16* Cout; int bn, bm, N, role;
    const int bid = blockIdx.x;
    if (bid < 512) { A = h1; Bm = wq; Cout = qk_b; N = 2048; bn = bid & 15; bm = bid >> 4; role = 0; }
    else {
        const int id = bid - 512;
        A = wq + (size_t)2 * 1024 * 1024;   // wv rows
        Bm = h1; Cout = vt_b; N = 4096; bn = id & 31; bm = id >> 5; role = 1;
    }
    constexpr int K = 1024;

    const int srow = lane >> 2;
    const int scol = (lane & 3) * 8;

    f32x4 acc[4][4] = {};

    for (int k0 = 0; k0 < K; k0 += 32) {
        #pragma unroll
        for (int c = 0; c < 2; ++c) {
            const int ch = wave * 2 + c;
            const u16* ga = A  + ((size_t)bm * 128 + ch * 16 + srow) * K + k0 + scol;
            gload_lds16(ga, &Alds[ch * 512]);
            const u16* gb = Bm + ((size_t)bn * 128 + ch * 16 + srow) * K + k0 + scol;
            gload_lds16(gb, &Blds[ch * 512]);
        }
        __syncthreads();
        bf16x8 af[4], bfr[4];
        #pragma unroll
        for (int m = 0; m < 4; ++m)
            af[m] = ldf(&Alds[(wr * 64 + m * 16 + r16) * 32 + g16 * 8]);
        #pragma unroll
        for (int n = 0; n < 4; ++n)
            bfr[n] = ldf(&Blds[(wc * 64 + n * 16 + r16) * 32 + g16 * 8]);
        #pragma unroll
        for (int m = 0; m < 4; ++m)
            #pragma unroll
            for (int n = 0; n < 4; ++n)
                acc[m][n] = mfma16(af[m], bfr[n], acc[m][n]);
        __syncthreads();
    }

    constexpr float SCQ = 0.125f * 1.44269504088896341f;
    #pragma unroll
    for (int m = 0; m < 4; ++m)
        #pragma unroll
        for (int n = 0; n < 4; ++n)
            #pragma unroll
            for (int r = 0; r < 4; ++r) {
                const int row = bm * 128 + wr * 64 + m * 16 + g16 * 4 + r;
                int col = bn * 128 + wc * 64 + n * 16 + r16;
                float v = acc[m][n][r];
                if (role == 0) {
                    if (col < 1024) v *= SCQ;                 // Q pre-scale
                } else {
                    const int c5 = col & 31;                   // PV permutation
                    const int pos = 8 * ((c5 & 15) >> 2) + 4 * (c5 >> 4) + (c5 & 3);
                    col = (col & ~31) | pos;
                }
                Cout[(size_t)row * N + col] = f2bf(v);
            }
}

// ---------- 128x128 GEMM, split-K bf16 partial planes (attn_out) ----------
__global__ __launch_bounds__(256) void gemm_btsplit_k(const u16* __restrict__ A,
                                                      const u16* __restrict__ Bm,
                                                      u16* __restrict__ P,
                                                      int N, int K, int kchunk,
                                                      int planeEls) {
    __shared__ alignas(16) u16 Alds[128 * 32];
    __shared__ alignas(16) u16 Blds[128 * 32];
    const int tid  = threadIdx.x;
    const int lane = tid & 63, wave = tid >> 6;
    const int wr = wave >> 1, wc = wave & 1;
    const int r16 = lane & 15, g16 = lane >> 4;
    const int bn = blockIdx.x, bm = blockIdx.y;
    const int kBeg = blockIdx.z * kchunk;

    const int srow = lane >> 2;
    const int scol = (lane & 3) * 8;

    f32x4 acc[4][4] = {};

    for (int k0 = kBeg; k0 < kBeg + kchunk; k0 += 32) {
        #pragma unroll
        for (int c = 0; c < 2; ++c) {
            const int ch = wave * 2 + c;
            const u16* ga = A  + ((size_t)bm * 128 + ch * 16 + srow) * K + k0 + scol;
            gload_lds16(ga, &Alds[ch * 512]);
            const u16* gb = Bm + ((size_t)bn * 128 + ch * 16 + srow) * K + k0 + scol;
            gload_lds16(gb, &Blds[ch * 512]);
        }
        __syncthreads();
        bf16x8 af[4], bfr[4];
        #pragma unroll
        for (int m = 0; m < 4; ++m)
            af[m] = ldf(&Alds[(wr * 64 + m * 16 + r16) * 32 + g16 * 8]);
        #pragma unroll
        for (int n = 0; n < 4; ++n)
            bfr[n] = ldf(&Blds[(wc * 64 + n * 16 + r16) * 32 + g16 * 8]);
        #pragma unroll
        for (int m = 0; m < 4; ++m)
            #pragma unroll
            for (int n = 0; n < 4; ++n)
                acc[m][n] = mfma16(af[m], bfr[n], acc[m][n]);
        __syncthreads();
    }

    u16* Pp = P + (size_t)blockIdx.z * planeEls;
    #pragma unroll
    for (int m = 0; m < 4; ++m)
        #pragma unroll
        for (int n = 0; n < 4; ++n)
            #pragma unroll
            for (int r = 0; r < 4; ++r) {
                const int row = bm * 128 + wr * 64 + m * 16 + g16 * 4 + r;
                const int col = bn * 128 + wc * 64 + n * 16 + r16;
                Pp[(size_t)row * N + col] = f2bf(acc[m][n][r]);
            }
}

// ---------- 256x256 GEMM v5: 64 KiB LDS (2-slot dbuf, BK=32) -> 2 blocks/CU ----------
// TLP instead of deep ILP: barrier/vmcnt drains of one block overlap with the
// co-resident block's MFMA (m114). Phase p: stage slot p^1 (4 gloads); read 12
// frags of slot p; 32 MFMA (setprio); vmcnt(0)+barrier.
// Slot layout: [256 rows][32 cols], 16B chunk c of row r stored at c^((r>>1)&3)
// (2-way bank spread = free); staging source pre-swizzled (both-sides rule).
// EPI 1: bf16 partials (plane blockIdx.z).  EPI 2: fused SwiGLU bf16.
template <int EPI>
__global__ __launch_bounds__(512, 2)
void gemm256_k(const u16* __restrict__ A, const u16* __restrict__ Bm,
               void* __restrict__ Cout, int lda, int ldb, int kLen,
               int nx, int bnCh, int outLd, int planeEls) {
    __shared__ alignas(16) u16 lds[2][2][8192];    // [slot][A/B][256*32] = 64 KiB

    const int tid  = threadIdx.x;
    const int wave = tid >> 6, lane = tid & 63;
    const int wm = wave >> 2, wn = wave & 3;
    const int r16 = lane & 15, g16 = lane >> 4;

    // 2D XCD chunking (gridDim.x % 8 == 0; nx % bnCh == 0; cpx % bnCh == 0)
    const int cpx = gridDim.x >> 3;
    const int xcd = blockIdx.x & 7, loc = blockIdx.x >> 3;
    const int mCh = cpx / bnCh;
    const int cpr = nx / bnCh;
    const int bm = (xcd / cpr) * mCh + loc / bnCh;
    const int bn = (xcd % cpr) * bnCh + loc % bnCh;
    const int kBeg = blockIdx.z * kLen;
    const int P = kLen >> 5;                       // K=32 phases

    // staging: linear chunk q = tid + i*512; row = q>>2; src chunk = (q&3)^((q>>3)&3)
    const u16* aU = A  + (size_t)(bm * 256) * lda + kBeg;
    const u16* bU = Bm + (size_t)(bn * 256) * ldb + kBeg;
    int aOf[2], bOf[2];
    #pragma unroll
    for (int i = 0; i < 2; ++i) {
        const int q = tid + i * 512;
        const int row = q >> 2;
        const int sc = (q & 3) ^ ((q >> 3) & 3);
        aOf[i] = row * lda + sc * 8;
        bOf[i] = row * ldb + sc * 8;
    }

    auto stage = [&](int p) {
        const int s = p & 1;
        const int ko = p * 32;
        u16* dA = &lds[s][0][wave * 512];
        u16* dB = &lds[s][1][wave * 512];
        gload_lds16(aU + aOf[0] + ko, dA);
        gload_lds16(aU + aOf[1] + ko, dA + 4096);
        gload_lds16(bU + bOf[0] + ko, dB);
        gload_lds16(bU + bOf[1] + ko, dB + 4096);
    };

    // fragment read offsets (u16 units), row-swizzled chunks
    int offA[8], offB[4];
    #pragma unroll
    for (int m = 0; m < 8; ++m) {
        const int r = wm * 128 + m * 16 + r16;
        offA[m] = r * 32 + ((g16 ^ ((r >> 1) & 3)) * 8);
    }
    #pragma unroll
    for (int n = 0; n < 4; ++n) {
        const int r = wn * 64 + n * 16 + r16;
        offB[n] = r * 32 + ((g16 ^ ((r >> 1) & 3)) * 8);
    }

    f32x4 acc[8][4] = {};

    stage(0);
    asm volatile("s_waitcnt vmcnt(0)" ::: "memory");
    __builtin_amdgcn_s_barrier();

    for (int p = 0; p < P; ++p) {
        const int s = p & 1;
        if (p + 1 < P) stage(p + 1);               // issue before reads (T3 recipe)
        bf16x8 af[8], bfr[4];
        const u16* PA = &lds[s][0][0];
        const u16* PB = &lds[s][1][0];
        #pragma unroll
        for (int m = 0; m < 8; ++m) af[m] = ldf(PA + offA[m]);
        #pragma unroll
        for (int n = 0; n < 4; ++n) bfr[n] = ldf(PB + offB[n]);
        __builtin_amdgcn_s_setprio(1);
        #pragma unroll
        for (int m = 0; m < 8; ++m)
            #pragma unroll
            for (int n = 0; n < 4; ++n)
                acc[m][n] = mfma16(af[m], bfr[n], acc[m][n]);
        __builtin_amdgcn_s_setprio(0);
        if (p + 1 < P) {
            asm volatile("s_waitcnt vmcnt(0)" ::: "memory");
            __builtin_amdgcn_s_barrier();
        }
    }

    if constexpr (EPI == 1) {
        u16* Pp = (u16*)Cout + (size_t)blockIdx.z * planeEls;
        #pragma unroll
        for (int m = 0; m < 8; ++m)
            #pragma unroll
            for (int n = 0; n < 4; ++n)
                #pragma unroll
                for (int r = 0; r < 4; ++r) {
                    const int row = bm * 256 + wm * 128 + m * 16 + g16 * 4 + r;
                    const int col = bn * 256 + wn * 64 + n * 16 + r16;
                    Pp[(size_t)row * outLd + col] = f2bf(acc[m][n][r]);
                }
    } else {
        (void)planeEls;
        u16* O = (u16*)Cout;
        #pragma unroll
        for (int m = 0; m < 8; ++m)
            #pragma unroll
            for (int n = 0; n < 2; ++n)
                #pragma unroll
                for (int r = 0; r < 4; ++r) {
                    const int row = bm * 256 + wm * 128 + m * 16 + g16 * 4 + r;
                    const int col = (bn * 4 + wn) * 32 + n * 16 + r16;
                    const float vi = acc[m][n][r];
                    const float vg = acc[m][n + 2][r];
                    const float sl = vi / (1.0f + __expf(-vi));
                    O[(size_t)row * outLd + col] = f2bf(sl * vg);
                }
    }
}

// ---------- split-K reduce: out = resid + sum of 8 bf16 planes ----------
__global__ __launch_bounds__(256) void addreduce8_k(const float* __restrict__ resid,
                                                    const u16* __restrict__ p,
                                                    float* __restrict__ out,
                                                    int n4, int planeEls) {
    for (int i = blockIdx.x * 256 + threadIdx.x; i < n4; i += gridDim.x * 256) {
        F4 a = *(const F4*)(resid + (size_t)i * 4);
        F4 o = a;
        #pragma unroll
        for (int pl = 0; pl < 8; ++pl) {
            U4 q = *(const U4*)(p + (size_t)pl * planeEls + (size_t)i * 4);
            #pragma unroll
            for (int j = 0; j < 4; ++j) o.v[j] += bf2f(q.v[j]);
        }
        *(F4*)(out + (size_t)i * 4) = o;
    }
}

// ---------- flash attention v4: paired q-tiles, permuted-V b128 PV,
// log2-domain softmax, defer-max rescale skip ----------
__global__ __launch_bounds__(256) void attn_fwd_k(const u16* __restrict__ qk,
                                                  const u16* __restrict__ vt,
                                                  u16* __restrict__ Ob) {
    __shared__ alignas(16) u16 Klds[2][64 * 64];
    __shared__ alignas(16) u16 Vlds[2][64 * 64];

    const int tid  = threadIdx.x;
    const int wave = tid >> 6, lane = tid & 63;
    const int r16  = lane & 15, g16 = lane >> 4;

    const int bh = blockIdx.x >> 4, pi = blockIdx.x & 15;
    const int h  = bh & 15, b = bh >> 4;
    const size_t seqb = (size_t)b * 2048;

    const u16* kbase = qk + seqb * 2048 + 1024 + (size_t)h * 64;
    const u16* vbase = vt + (size_t)(h * 64) * 4096 + seqb;

    const int srow  = tid >> 3;                           // 0..31
    const int scol8 = ((tid & 7) ^ (srow & 7)) * 8;
    const u16* ksrc = kbase + (size_t)srow * 2048 + scol8;
    const u16* vsrc = vbase + (size_t)srow * 4096 + scol8;

    auto stage = [&](int bufi, int kv0) {
        const u16* kp = ksrc + (size_t)kv0 * 2048;
        const u16* vp = vsrc + kv0;
        u16* kd = &Klds[bufi][wave * 512];
        u16* vd = &Vlds[bufi][wave * 512];
        gload_lds16(kp, kd);
        gload_lds16(kp + (size_t)32 * 2048, kd + 2048);
        gload_lds16(vp, vd);
        gload_lds16(vp + (size_t)32 * 4096, vd + 2048);
    };

    #pragma unroll 1
    for (int half = 0; half < 2; ++half) {
        const int qb  = half ? pi : (31 - pi);            // long tile first
        const int q0w = qb * 64 + wave * 16;

        const u16* qp = qk + (seqb + q0w + r16) * 2048 + h * 64 + g16 * 8;
        const bf16x8 qf0 = *(const bf16x8*)qp;            // Q pre-scaled by 0.125*log2e
        const bf16x8 qf1 = *(const bf16x8*)(qp + 32);

        f32x4 o[4] = {};
        float mreg = -3.0e38f, lreg = 0.0f;
        const int nt = qb + 1;

        if (half) __syncthreads();                        // protect LDS vs prev half
        stage(0, 0);
        asm volatile("s_waitcnt vmcnt(0)" ::: "memory");
        __builtin_amdgcn_s_barrier();

        for (int it = 0; it < nt; ++it) {
            const int kv0 = it * 64;
            const int cur = it & 1;
            if (it + 1 < nt) stage(cur ^ 1, kv0 + 64);

            const u16* K = Klds[cur];
            const u16* V = Vlds[cur];

            f32x4 s[4];
            #pragma unroll
            for (int t = 0; t < 4; ++t) {
                const int row = 16 * t + r16;
                const int sw  = row & 7;
                const bf16x8 k0 = ldf(&K[row * 64 + ((g16 ^ sw) * 8)]);
                const bf16x8 k1 = ldf(&K[row * 64 + (((g16 + 4) ^ sw) * 8)]);
                f32x4 acc = {0.f, 0.f, 0.f, 0.f};
                acc = mfma16(k0, qf0, acc);
                acc = mfma16(k1, qf1, acc);
                s[t] = acc;
            }

            float a[16];
            #pragma unroll
            for (int t = 0; t < 4; ++t)
                #pragma unroll
                for (int r = 0; r < 4; ++r) a[4 * t + r] = s[t][r];

            if (kv0 + 63 > q0w) {                         // wave-uniform causal branch
                const int qg = q0w + r16;
                #pragma unroll
                for (int t = 0; t < 4; ++t)
                    #pragma unroll
                    for (int r = 0; r < 4; ++r)
                        if (kv0 + 16 * t + 4 * g16 + r > qg) a[4 * t + r] = -1.0e30f;
            }

            float mx = a[0];
            #pragma unroll
            for (int j = 1; j < 16; ++j) mx = fmaxf(mx, a[j]);
            mx = fmaxf(mx, __shfl_xor(mx, 16));
            mx = fmaxf(mx, __shfl_xor(mx, 32));

            const float mn = fmaxf(mreg, mx);
            float p[16], rs = 0.0f;
            #pragma unroll
            for (int j = 0; j < 16; ++j) { p[j] = exp2f(a[j] - mn); rs += p[j]; }
            rs += __shfl_xor(rs, 16);
            rs += __shfl_xor(rs, 32);

            if (__all(mx <= mreg)) {                      // defer-max: no rescale
                lreg += rs;
            } else {
                const float al = exp2f(mreg - mn);
                lreg = lreg * al + rs;
                mreg = mn;
                #pragma unroll
                for (int t = 0; t < 4; ++t)
                    #pragma unroll
                    for (int r = 0; r < 4; ++r) o[t][r] *= al;
            }

            bf16x8 pf0, pf1;
            #pragma unroll
            for (int j = 0; j < 8; ++j) { pf0[j] = (__bf16)p[j]; pf1[j] = (__bf16)p[8 + j]; }

            // PV: permuted-V layout -> one b128 per (t, half32)
            #pragma unroll
            for (int t = 0; t < 4; ++t) {
                const int row = 16 * t + r16;
                const int sw  = row & 7;
                const bf16x8 v0 = ldf(&V[row * 64 + ((g16 ^ sw) * 8)]);
                const bf16x8 v1 = ldf(&V[row * 64 + (((4 + g16) ^ sw) * 8)]);
                o[t] = mfma16(v0, pf0, o[t]);
                o[t] = mfma16(v1, pf1, o[t]);
            }

            if (it + 1 < nt) {
                asm volatile("s_waitcnt vmcnt(0)" ::: "memory");
                __builtin_amdgcn_s_barrier();
            }
        }

        const float inv = 1.0f / lreg;
        u16* op = Ob + (seqb + q0w + r16) * 1024 + h * 64 + 4 * g16;
        #pragma unroll
        for (int t = 0; t < 4; ++t) {
            U4 st;
            #pragma unroll
            for (int r = 0; r < 4; ++r) st.v[r] = f2bf(o[t][r] * inv);
            *(U4*)(op + 16 * t) = st;
        }
    }
}

// ---------- launch ----------
extern "C" void kernel_launch(void* const* d_in, const int* in_sizes, int n_in,
                              void* d_out, int out_size, void* d_ws, size_t ws_size,
                              hipStream_t stream) {
    (void)in_sizes; (void)n_in; (void)out_size; (void)ws_size;
    constexpr int C = 1024, FF = 4096, M = 2 * 2048;   // B*T = 4096
    constexpr size_t MB = 1024 * 1024;

    const float* x      = (const float*)d_in[0];
    const float* ln1_w  = (const float*)d_in[1];
    const float* ln1_b  = (const float*)d_in[2];
    const float* qkv_w  = (const float*)d_in[3];
    const float* atto_w = (const float*)d_in[4];
    const float* ln2_w  = (const float*)d_in[5];
    const float* ln2_b  = (const float*)d_in[6];
    const float* mlpi_w = (const float*)d_in[7];
    const float* mlpg_w = (const float*)d_in[8];
    const float* mlpo_w = (const float*)d_in[9];
    float* out = (float*)d_out;

    char* ws = (char*)d_ws;
    size_t off = 0;
    auto alloc = [&](size_t bytes) {
        char* p = ws + off;
        off += (bytes + 255) & ~(size_t)255;
        return p;
    };
    u16*   wq   = (u16*)  alloc((size_t)3 * C * C * 2);   // qkv_w bf16 (Q,K rows then V)
    u16*   wo   = (u16*)  alloc((size_t)C * C * 2);
    u16*   wig  = (u16*)  alloc((size_t)2 * FF * C * 2);  // interleaved wi/wg [8192][1024]
    u16*   wm   = (u16*)  alloc((size_t)C * FF * 2);
    float* x1   = (float*)alloc((size_t)M * C * 4);
    u16*   h2   = (u16*)  alloc((size_t)M * C * 2);
    u16*   ab   = (u16*)  alloc((size_t)M * FF * 2);
    // region R (64 MB): attn-phase buffers; later reused for mlpo partials
    char*  R    = alloc(64 * MB);
    u16*   h1   = (u16*)R;                 //  8 MB
    u16*   qk_b = (u16*)(R + 8 * MB);      // 16 MB  [4096][2048] Q|K
    u16*   vt_b = (u16*)(R + 24 * MB);     //  8 MB  [1024][4096] V^T (PV-permuted)
    u16*   Ob   = (u16*)(R + 32 * MB);     //  8 MB
    u16*   aoP  = (u16*)(R + 40 * MB);     // 16 MB  attn_out bf16 partials (2 planes)
    u16*   pscr = (u16*)R;                 // 64 MB  mlpo bf16 partials (8 planes) — after attn

    // all weight casts (one kernel)
    cast_all_k<<<8192, 256, 0, stream>>>(qkv_w, atto_w, mlpo_w, mlpi_w, mlpg_w,
                                         wq, wo, wm, wig);

    // attention branch
    ln_fwd_k<<<M, 256, 0, stream>>>(x, ln1_w, ln1_b, h1);
    gemm_qkvt_k<<<768, 256, 0, stream>>>(h1, wq, qk_b, vt_b);
    attn_fwd_k<<<512, 256, 0, stream>>>(qk_b, vt_b, Ob);
    // attn_out: split-K=2 bf16 partials (512 blocks = 2/CU)
    gemm_btsplit_k<<<dim3(C / 128, M / 128, 2), 256, 0, stream>>>(
        Ob, wo, aoP, C, C, C / 2, M * C);
    // fused residual+LN2: x1 = x + p0 + p1 ; h2 = LN(x1)
    ln_resid_k<<<M, 256, 0, stream>>>(x, aoP, ln2_w, ln2_b, x1, h2, M * C);

    // MLP branch (64 KiB-LDS v5 kernels, 2 blocks/CU)
    gemm256_k<2><<<dim3((2 * FF / 256) * (M / 256), 1, 1), 512, 0, stream>>>(
        h2, wig, ab, C, C, C, 2 * FF / 256, 8, FF, 0);
    // mlp_out: split-K=8 (grid 4x16 x8 = 512 blocks = 2/CU), bf16 partials
    gemm256_k<1><<<dim3((C / 256) * (M / 256), 1, 8), 512, 0, stream>>>(
        ab, wm, pscr, FF, FF, FF / 8, C / 256, 4, C, M * C);
    addreduce8_k<<<2048, 256, 0, stream>>>(x1, pscr, out, M * C / 4, M * C);
}

// Round 13
// 249.643 us; speedup vs baseline: 1.0613x; 1.0613x over previous
//
#include <hip/hip_runtime.h>
#include <cstdint>

// ---------- types & helpers ----------
typedef unsigned short u16;
typedef __bf16 bf16x8 __attribute__((ext_vector_type(8)));
typedef float  f32x4  __attribute__((ext_vector_type(4)));

struct alignas(16) F4 { float v[4]; };
struct alignas(8)  U4 { u16 v[4]; };
struct alignas(16) U8 { u16 v[8]; };

__device__ __forceinline__ u16 f2bf(float f) {
    union { float f; unsigned int u; } x; x.f = f;
    unsigned int r = x.u + 0x7fffu + ((x.u >> 16) & 1u);   // RNE
    return (u16)(r >> 16);
}
__device__ __forceinline__ float bf2f(u16 u) {
    union { unsigned int u; float f; } x; x.u = ((unsigned int)u) << 16;
    return x.f;
}
__device__ __forceinline__ f32x4 mfma16(bf16x8 a, bf16x8 b, f32x4 c) {
    return __builtin_amdgcn_mfma_f32_16x16x32_bf16(a, b, c, 0, 0, 0);
}
__device__ __forceinline__ bf16x8 ldf(const u16* p) { return *(const bf16x8*)p; }
// async global->LDS, 16B per lane, dest = wave-uniform base + lane*16
__device__ __forceinline__ void gload_lds16(const void* g, void* l) {
    auto* gp = reinterpret_cast<const __attribute__((address_space(1))) unsigned int*>(
        reinterpret_cast<uintptr_t>(g));
    auto* lp = reinterpret_cast<__attribute__((address_space(3))) unsigned int*>(
        reinterpret_cast<uintptr_t>(l));
    __builtin_amdgcn_global_load_lds(gp, lp, 16, 0, 0);
}

// ---------- ALL weight casts in one kernel ----------
__global__ __launch_bounds__(256) void cast_all_k(const float* __restrict__ qkvw,
                                                  const float* __restrict__ attow,
                                                  const float* __restrict__ mlpow,
                                                  const float* __restrict__ wi,
                                                  const float* __restrict__ wg,
                                                  u16* __restrict__ wq,
                                                  u16* __restrict__ wo,
                                                  u16* __restrict__ wm,
                                                  u16* __restrict__ wig) {
    constexpr int N1 = 3 * 1024 * 1024 / 8;            // wq units-of-8
    constexpr int N2 = N1 + 1024 * 1024 / 8;           // +wo
    constexpr int N3 = N2 + 1024 * 4096 / 8;           // +wm
    const int i = blockIdx.x * 256 + threadIdx.x;
    const float* src; u16* dst;
    if (i < N1)      { src = qkvw  + (size_t)i * 8;        dst = wq + (size_t)i * 8; }
    else if (i < N2) { const int j = i - N1; src = attow + (size_t)j * 8; dst = wo + (size_t)j * 8; }
    else if (i < N3) { const int j = i - N2; src = mlpow + (size_t)j * 8; dst = wm + (size_t)j * 8; }
    else {
        const int j = i - N3;
        const int w = j >> 7, c8 = (j & 127) * 8;
        const int f = ((w >> 6) << 5) | (w & 31);
        src = ((w & 32) ? wg : wi) + (size_t)f * 1024 + c8;
        dst = wig + (size_t)w * 1024 + c8;
    }
    F4 a = *(const F4*)src;
    F4 b = *(const F4*)(src + 4);
    U8 o;
    #pragma unroll
    for (int j = 0; j < 4; ++j) { o.v[j] = f2bf(a.v[j]); o.v[4 + j] = f2bf(b.v[j]); }
    *(U8*)dst = o;
}

// ---------- LayerNorm (C=1024), f32 in -> bf16 out ----------
__global__ __launch_bounds__(256) void ln_fwd_k(const float* __restrict__ x,
                                                const float* __restrict__ w,
                                                const float* __restrict__ b,
                                                u16* __restrict__ h) {
    const int row = blockIdx.x, tid = threadIdx.x;
    const float* xr = x + (size_t)row * 1024;
    F4 v = *(const F4*)(xr + tid * 4);
    float s  = v.v[0] + v.v[1] + v.v[2] + v.v[3];
    float ss = v.v[0]*v.v[0] + v.v[1]*v.v[1] + v.v[2]*v.v[2] + v.v[3]*v.v[3];
    #pragma unroll
    for (int o = 32; o > 0; o >>= 1) { s += __shfl_down(s, o); ss += __shfl_down(ss, o); }
    __shared__ float red[8];
    const int wave = tid >> 6, lane = tid & 63;
    if (lane == 0) { red[wave] = s; red[4 + wave] = ss; }
    __syncthreads();
    s  = red[0] + red[1] + red[2] + red[3];
    ss = red[4] + red[5] + red[6] + red[7];
    const float mu   = s * (1.0f / 1024.0f);
    const float var  = ss * (1.0f / 1024.0f) - mu * mu;
    const float rstd = rsqrtf(var + 1e-5f);
    U4 o;
    #pragma unroll
    for (int j = 0; j < 4; ++j)
        o.v[j] = f2bf((v.v[j] - mu) * rstd * w[tid * 4 + j] + b[tid * 4 + j]);
    *(U4*)(h + (size_t)row * 1024 + tid * 4) = o;
}

// ---------- fused residual + LN2: x1 = x + p0 + p1 (bf16 planes); h2 = LN(x1) ----------
__global__ __launch_bounds__(256) void ln_resid_k(const float* __restrict__ x,
                                                  const u16* __restrict__ p,
                                                  const float* __restrict__ w,
                                                  const float* __restrict__ b,
                                                  float* __restrict__ x1,
                                                  u16* __restrict__ h,
                                                  int planeEls) {
    const int row = blockIdx.x, tid = threadIdx.x;
    const size_t base = (size_t)row * 1024 + tid * 4;
    F4 xv = *(const F4*)(x + base);
    U4 q0 = *(const U4*)(p + base);
    U4 q1 = *(const U4*)(p + (size_t)planeEls + base);
    F4 sv;
    #pragma unroll
    for (int j = 0; j < 4; ++j) sv.v[j] = xv.v[j] + bf2f(q0.v[j]) + bf2f(q1.v[j]);
    *(F4*)(x1 + base) = sv;
    float s  = sv.v[0] + sv.v[1] + sv.v[2] + sv.v[3];
    float ss = sv.v[0]*sv.v[0] + sv.v[1]*sv.v[1] + sv.v[2]*sv.v[2] + sv.v[3]*sv.v[3];
    #pragma unroll
    for (int o = 32; o > 0; o >>= 1) { s += __shfl_down(s, o); ss += __shfl_down(ss, o); }
    __shared__ float red[8];
    const int wave = tid >> 6, lane = tid & 63;
    if (lane == 0) { red[wave] = s; red[4 + wave] = ss; }
    __syncthreads();
    s  = red[0] + red[1] + red[2] + red[3];
    ss = red[4] + red[5] + red[6] + red[7];
    const float mu   = s * (1.0f / 1024.0f);
    const float var  = ss * (1.0f / 1024.0f) - mu * mu;
    const float rstd = rsqrtf(var + 1e-5f);
    U4 o;
    #pragma unroll
    for (int j = 0; j < 4; ++j)
        o.v[j] = f2bf((sv.v[j] - mu) * rstd * w[tid * 4 + j] + b[tid * 4 + j]);
    *(U4*)(h + base) = o;
}

// ---------- combined qk + vt GEMM (one dispatch, 768 blocks) ----------
__global__ __launch_bounds__(256) void gemm_qkvt_k(const u16* __restrict__ h1,
                                                   const u16* __restrict__ wq,
                                                   u16* __restrict__ qk_b,
                                                   u16* __restrict__ vt_b) {
    __shared__ alignas(16) u16 Alds[128 * 32];
    __shared__ alignas(16) u16 Blds[128 * 32];
    const int tid  = threadIdx.x;
    const int lane = tid & 63, wave = tid >> 6;
    const int wr = wave >> 1, wc = wave & 1;
    const int r16 = lane & 15, g16 = lane >> 4;

    const u16* A; const u16* Bm; u16* Cout; int bn, bm, N, role;
    const int bid = blockIdx.x;
    if (bid < 512) { A = h1; Bm = wq; Cout = qk_b; N = 2048; bn = bid & 15; bm = bid >> 4; role = 0; }
    else {
        const int id = bid - 512;
        A = wq + (size_t)2 * 1024 * 1024;   // wv rows
        Bm = h1; Cout = vt_b; N = 4096; bn = id & 31; bm = id >> 5; role = 1;
    }
    constexpr int K = 1024;

    const int srow = lane >> 2;
    const int scol = (lane & 3) * 8;

    f32x4 acc[4][4] = {};

    for (int k0 = 0; k0 < K; k0 += 32) {
        #pragma unroll
        for (int c = 0; c < 2; ++c) {
            const int ch = wave * 2 + c;
            const u16* ga = A  + ((size_t)bm * 128 + ch * 16 + srow) * K + k0 + scol;
            gload_lds16(ga, &Alds[ch * 512]);
            const u16* gb = Bm + ((size_t)bn * 128 + ch * 16 + srow) * K + k0 + scol;
            gload_lds16(gb, &Blds[ch * 512]);
        }
        __syncthreads();
        bf16x8 af[4], bfr[4];
        #pragma unroll
        for (int m = 0; m < 4; ++m)
            af[m] = ldf(&Alds[(wr * 64 + m * 16 + r16) * 32 + g16 * 8]);
        #pragma unroll
        for (int n = 0; n < 4; ++n)
            bfr[n] = ldf(&Blds[(wc * 64 + n * 16 + r16) * 32 + g16 * 8]);
        #pragma unroll
        for (int m = 0; m < 4; ++m)
            #pragma unroll
            for (int n = 0; n < 4; ++n)
                acc[m][n] = mfma16(af[m], bfr[n], acc[m][n]);
        __syncthreads();
    }

    constexpr float SCQ = 0.125f * 1.44269504088896341f;
    #pragma unroll
    for (int m = 0; m < 4; ++m)
        #pragma unroll
        for (int n = 0; n < 4; ++n)
            #pragma unroll
            for (int r = 0; r < 4; ++r) {
                const int row = bm * 128 + wr * 64 + m * 16 + g16 * 4 + r;
                int col = bn * 128 + wc * 64 + n * 16 + r16;
                float v = acc[m][n][r];
                if (role == 0) {
                    if (col < 1024) v *= SCQ;                 // Q pre-scale
                } else {
                    const int c5 = col & 31;                   // PV permutation
                    const int pos = 8 * ((c5 & 15) >> 2) + 4 * (c5 >> 4) + (c5 & 3);
                    col = (col & ~31) | pos;
                }
                Cout[(size_t)row * N + col] = f2bf(v);
            }
}

// ---------- 128x128 GEMM, split-K bf16 partial planes (attn_out) ----------
__global__ __launch_bounds__(256) void gemm_btsplit_k(const u16* __restrict__ A,
                                                      const u16* __restrict__ Bm,
                                                      u16* __restrict__ P,
                                                      int N, int K, int kchunk,
                                                      int planeEls) {
    __shared__ alignas(16) u16 Alds[128 * 32];
    __shared__ alignas(16) u16 Blds[128 * 32];
    const int tid  = threadIdx.x;
    const int lane = tid & 63, wave = tid >> 6;
    const int wr = wave >> 1, wc = wave & 1;
    const int r16 = lane & 15, g16 = lane >> 4;
    const int bn = blockIdx.x, bm = blockIdx.y;
    const int kBeg = blockIdx.z * kchunk;

    const int srow = lane >> 2;
    const int scol = (lane & 3) * 8;

    f32x4 acc[4][4] = {};

    for (int k0 = kBeg; k0 < kBeg + kchunk; k0 += 32) {
        #pragma unroll
        for (int c = 0; c < 2; ++c) {
            const int ch = wave * 2 + c;
            const u16* ga = A  + ((size_t)bm * 128 + ch * 16 + srow) * K + k0 + scol;
            gload_lds16(ga, &Alds[ch * 512]);
            const u16* gb = Bm + ((size_t)bn * 128 + ch * 16 + srow) * K + k0 + scol;
            gload_lds16(gb, &Blds[ch * 512]);
        }
        __syncthreads();
        bf16x8 af[4], bfr[4];
        #pragma unroll
        for (int m = 0; m < 4; ++m)
            af[m] = ldf(&Alds[(wr * 64 + m * 16 + r16) * 32 + g16 * 8]);
        #pragma unroll
        for (int n = 0; n < 4; ++n)
            bfr[n] = ldf(&Blds[(wc * 64 + n * 16 + r16) * 32 + g16 * 8]);
        #pragma unroll
        for (int m = 0; m < 4; ++m)
            #pragma unroll
            for (int n = 0; n < 4; ++n)
                acc[m][n] = mfma16(af[m], bfr[n], acc[m][n]);
        __syncthreads();
    }

    u16* Pp = P + (size_t)blockIdx.z * planeEls;
    #pragma unroll
    for (int m = 0; m < 4; ++m)
        #pragma unroll
        for (int n = 0; n < 4; ++n)
            #pragma unroll
            for (int r = 0; r < 4; ++r) {
                const int row = bm * 128 + wr * 64 + m * 16 + g16 * 4 + r;
                const int col = bn * 128 + wc * 64 + n * 16 + r16;
                Pp[(size_t)row * N + col] = f2bf(acc[m][n][r]);
            }
}

// ---------- 256x256 pipelined GEMM v3 (frag-prefetch; best measured) ----------
template <int EPI>
__global__ __launch_bounds__(512, 2)
void gemm256_k(const u16* __restrict__ A, const u16* __restrict__ Bm,
               void* __restrict__ Cout, int lda, int ldb, int kLen,
               int nx, int bnCh, int outLd, int planeEls) {
    __shared__ alignas(16) u16 lds[2][2][2][128 * 64];

    const int tid  = threadIdx.x;
    const int wave = tid >> 6, lane = tid & 63;
    const int wm = wave >> 2, wn = wave & 3;
    const int r16 = lane & 15, g16 = lane >> 4;

    const int cpx = gridDim.x >> 3;
    const int xcd = blockIdx.x & 7, loc = blockIdx.x >> 3;
    const int mCh = cpx / bnCh;
    const int cpr = nx / bnCh;
    const int bm = (xcd / cpr) * mCh + loc / bnCh;
    const int bn = (xcd % cpr) * bnCh + loc % bnCh;
    const int kBeg = blockIdx.z * kLen;
    const int NT = kLen >> 6;

    const int csw = ((lane & 7) ^ (lane >> 3)) * 8;
    const u16* aU = A  + (size_t)(bm * 256) * lda + kBeg;
    const u16* bU = Bm + (size_t)(bn * 256) * ldb + kBeg;
    int aOff[2][2], bOff[2][2];
    #pragma unroll
    for (int h = 0; h < 2; ++h)
        #pragma unroll
        for (int i = 0; i < 2; ++i) {
            const int wr = wave * 16 + (lane >> 3) + i * 8;
            const int ar = (wr >> 6) * 128 + h * 64 + (wr & 63);
            const int br = (wr >> 5) * 64 + h * 32 + (wr & 31);
            aOff[h][i] = ar * lda + csw;
            bOff[h][i] = br * ldb + csw;
        }

    auto stA = [&](int kt, int h) {
        u16* d = &lds[kt & 1][0][h][wave * 1024];
        gload_lds16(aU + aOff[h][0] + kt * 64, d);
        gload_lds16(aU + aOff[h][1] + kt * 64, d + 512);
    };
    auto stB = [&](int kt, int h) {
        u16* d = &lds[kt & 1][1][h][wave * 1024];
        gload_lds16(bU + bOff[h][0] + kt * 64, d);
        gload_lds16(bU + bOff[h][1] + kt * 64, d + 512);
    };

    int offA[4][2], offB[2][2];
    #pragma unroll
    for (int m = 0; m < 4; ++m)
        #pragma unroll
        for (int ks = 0; ks < 2; ++ks)
            offA[m][ks] = (wm * 64 + m * 16 + r16) * 64 + (((ks * 4 + g16) ^ (r16 & 7)) * 8);
    #pragma unroll
    for (int n = 0; n < 2; ++n)
        #pragma unroll
        for (int ks = 0; ks < 2; ++ks)
            offB[n][ks] = (wn * 32 + n * 16 + r16) * 64 + (((ks * 4 + g16) ^ (r16 & 7)) * 8);

    f32x4 acc[8][4] = {};
    bf16x8 af0[4][2], af1[4][2], b0v[2][2], b1v[2][2];

    auto rdAF0 = [&](int buf) {
        const u16* P = &lds[buf][0][0][0];
        #pragma unroll
        for (int m = 0; m < 4; ++m) { af0[m][0] = ldf(P + offA[m][0]); af0[m][1] = ldf(P + offA[m][1]); }
    };
    auto rdAF1 = [&](int buf) {
        const u16* P = &lds[buf][0][1][0];
        #pragma unroll
        for (int m = 0; m < 4; ++m) { af1[m][0] = ldf(P + offA[m][0]); af1[m][1] = ldf(P + offA[m][1]); }
    };
    auto rdB0 = [&](int buf) {
        const u16* P = &lds[buf][1][0][0];
        #pragma unroll
        for (int n = 0; n < 2; ++n) { b0v[n][0] = ldf(P + offB[n][0]); b0v[n][1] = ldf(P + offB[n][1]); }
    };
    auto rdB1 = [&](int buf) {
        const u16* P = &lds[buf][1][1][0];
        #pragma unroll
        for (int n = 0; n < 2; ++n) { b1v[n][0] = ldf(P + offB[n][0]); b1v[n][1] = ldf(P + offB[n][1]); }
    };

    stA(0, 0); stB(0, 0); stB(0, 1); stA(0, 1);
    stA(1, 0); stB(1, 0); stB(1, 1); stA(1, 1);
    asm volatile("s_waitcnt vmcnt(8)" ::: "memory");
    __builtin_amdgcn_s_barrier();
    rdAF0(0); rdB0(0); rdB1(0); rdAF1(0);

    for (int kt = 0; kt < NT; ++kt) {
        const bool pf = (kt + 2 < NT);
        const int nb = (kt + 1) & 1;

        __builtin_amdgcn_s_setprio(1);
        #pragma unroll
        for (int m = 0; m < 4; ++m)
            #pragma unroll
            for (int n = 0; n < 2; ++n) {
                acc[m][n] = mfma16(af0[m][0], b0v[n][0], acc[m][n]);
                acc[m][n] = mfma16(af0[m][1], b0v[n][1], acc[m][n]);
            }
        __builtin_amdgcn_s_setprio(0);
        __builtin_amdgcn_s_barrier();

        if (pf) { stA(kt + 2, 0); stB(kt + 2, 0); }
        __builtin_amdgcn_s_setprio(1);
        #pragma unroll
        for (int m = 0; m < 4; ++m)
            #pragma unroll
            for (int n = 0; n < 2; ++n) {
                acc[m][n + 2] = mfma16(af0[m][0], b1v[n][0], acc[m][n + 2]);
                acc[m][n + 2] = mfma16(af0[m][1], b1v[n][1], acc[m][n + 2]);
            }
        __builtin_amdgcn_s_setprio(0);
        __builtin_amdgcn_s_barrier();

        if (pf) stB(kt + 2, 1);
        __builtin_amdgcn_s_setprio(1);
        #pragma unroll
        for (int m = 0; m < 4; ++m)
            #pragma unroll
            for (int n = 0; n < 2; ++n) {
                acc[m + 4][n] = mfma16(af1[m][0], b0v[n][0], acc[m + 4][n]);
                acc[m + 4][n] = mfma16(af1[m][1], b0v[n][1], acc[m + 4][n]);
            }
        __builtin_amdgcn_s_setprio(0);
        __builtin_amdgcn_s_barrier();

        if (pf) stA(kt + 2, 1);
        if (pf)               { asm volatile("s_waitcnt vmcnt(8)" ::: "memory"); }
        else if (kt + 1 < NT) { asm volatile("s_waitcnt vmcnt(0)" ::: "memory"); }
        if (kt + 1 < NT) {
            __builtin_amdgcn_s_barrier();
            rdAF0(nb); rdB0(nb);
        }
        __builtin_amdgcn_s_setprio(1);
        #pragma unroll
        for (int m = 0; m < 4; ++m)
            #pragma unroll
            for (int n = 0; n < 2; ++n) {
                acc[m + 4][n + 2] = mfma16(af1[m][0], b1v[n][0], acc[m + 4][n + 2]);
                acc[m + 4][n + 2] = mfma16(af1[m][1], b1v[n][1], acc[m + 4][n + 2]);
            }
        __builtin_amdgcn_s_setprio(0);
        if (kt + 1 < NT) { rdB1(nb); rdAF1(nb); }
    }

    if constexpr (EPI == 1) {
        u16* P = (u16*)Cout + (size_t)blockIdx.z * planeEls;
        #pragma unroll
        for (int m = 0; m < 8; ++m)
            #pragma unroll
            for (int n = 0; n < 4; ++n)
                #pragma unroll
                for (int r = 0; r < 4; ++r) {
                    const int row = bm * 256 + wm * 128 + m * 16 + g16 * 4 + r;
                    const int col = bn * 256 + wn * 64 + n * 16 + r16;
                    P[(size_t)row * outLd + col] = f2bf(acc[m][n][r]);
                }
    } else {
        (void)planeEls;
        u16* O = (u16*)Cout;
        #pragma unroll
        for (int m = 0; m < 8; ++m)
            #pragma unroll
            for (int n = 0; n < 2; ++n)
                #pragma unroll
                for (int r = 0; r < 4; ++r) {
                    const int row = bm * 256 + wm * 128 + m * 16 + g16 * 4 + r;
                    const int col = (bn * 4 + wn) * 32 + n * 16 + r16;
                    const float vi = acc[m][n][r];
                    const float vg = acc[m][n + 2][r];
                    const float sl = vi / (1.0f + __expf(-vi));
                    O[(size_t)row * outLd + col] = f2bf(sl * vg);
                }
    }
}

// ---------- split-K reduce: out = resid + sum of 4 bf16 planes ----------
__global__ __launch_bounds__(256) void addreduce4_k(const float* __restrict__ resid,
                                                    const u16* __restrict__ p,
                                                    float* __restrict__ out,
                                                    int n4, int planeEls) {
    for (int i = blockIdx.x * 256 + threadIdx.x; i < n4; i += gridDim.x * 256) {
        F4 a = *(const F4*)(resid + (size_t)i * 4);
        U4 q0 = *(const U4*)(p + (size_t)i * 4);
        U4 q1 = *(const U4*)(p + (size_t)planeEls + (size_t)i * 4);
        U4 q2 = *(const U4*)(p + (size_t)2 * planeEls + (size_t)i * 4);
        U4 q3 = *(const U4*)(p + (size_t)3 * planeEls + (size_t)i * 4);
        F4 o;
        #pragma unroll
        for (int j = 0; j < 4; ++j)
            o.v[j] = a.v[j] + bf2f(q0.v[j]) + bf2f(q1.v[j]) + bf2f(q2.v[j]) + bf2f(q3.v[j]);
        *(F4*)(out + (size_t)i * 4) = o;
    }
}

// ---------- flash attention v5: paired q-tiles, permuted-V b128 PV, log2 softmax,
// defer-max, 3-slot KV ring with counted vmcnt(4) (T4: never drain mid-loop) ----------
__global__ __launch_bounds__(256) void attn_fwd_k(const u16* __restrict__ qk,
                                                  const u16* __restrict__ vt,
                                                  u16* __restrict__ Ob) {
    __shared__ alignas(16) u16 Klds[3][64 * 64];
    __shared__ alignas(16) u16 Vlds[3][64 * 64];

    const int tid  = threadIdx.x;
    const int wave = tid >> 6, lane = tid & 63;
    const int r16  = lane & 15, g16 = lane >> 4;

    const int bh = blockIdx.x >> 4, pi = blockIdx.x & 15;
    const int h  = bh & 15, b = bh >> 4;
    const size_t seqb = (size_t)b * 2048;

    const u16* kbase = qk + seqb * 2048 + 1024 + (size_t)h * 64;
    const u16* vbase = vt + (size_t)(h * 64) * 4096 + seqb;

    const int srow  = tid >> 3;                           // 0..31
    const int scol8 = ((tid & 7) ^ (srow & 7)) * 8;
    const u16* ksrc = kbase + (size_t)srow * 2048 + scol8;
    const u16* vsrc = vbase + (size_t)srow * 4096 + scol8;

    auto stage = [&](int slot, int kv0) {
        const u16* kp = ksrc + (size_t)kv0 * 2048;
        const u16* vp = vsrc + kv0;
        u16* kd = &Klds[slot][wave * 512];
        u16* vd = &Vlds[slot][wave * 512];
        gload_lds16(kp, kd);
        gload_lds16(kp + (size_t)32 * 2048, kd + 2048);
        gload_lds16(vp, vd);
        gload_lds16(vp + (size_t)32 * 4096, vd + 2048);
    };

    #pragma unroll 1
    for (int half = 0; half < 2; ++half) {
        const int qb  = half ? pi : (31 - pi);            // long tile first
        const int q0w = qb * 64 + wave * 16;

        const u16* qp = qk + (seqb + q0w + r16) * 2048 + h * 64 + g16 * 8;
        const bf16x8 qf0 = *(const bf16x8*)qp;            // Q pre-scaled by 0.125*log2e
        const bf16x8 qf1 = *(const bf16x8*)(qp + 32);

        f32x4 o[4] = {};
        float mreg = -3.0e38f, lreg = 0.0f;
        const int nt = qb + 1;

        if (half) __syncthreads();                        // protect LDS vs prev half
        stage(0, 0);
        if (nt > 1) {
            stage(1, 64);
            asm volatile("s_waitcnt vmcnt(4)" ::: "memory");   // slot0 ready, slot1 in flight
        } else {
            asm volatile("s_waitcnt vmcnt(0)" ::: "memory");
        }
        __builtin_amdgcn_s_barrier();

        int cur = 0, nx2 = 2;                             // slot of it, slot of it+2
        for (int it = 0; it < nt; ++it) {
            const int kv0 = it * 64;
            const bool pf = (it + 2 < nt);
            if (pf) stage(nx2, kv0 + 128);                // into slot (it-1)%3: reads done

            const u16* K = Klds[cur];
            const u16* V = Vlds[cur];

            f32x4 s[4];
            #pragma unroll
            for (int t = 0; t < 4; ++t) {
                const int row = 16 * t + r16;
                const int sw  = row & 7;
                const bf16x8 k0 = ldf(&K[row * 64 + ((g16 ^ sw) * 8)]);
                const bf16x8 k1 = ldf(&K[row * 64 + (((g16 + 4) ^ sw) * 8)]);
                f32x4 acc = {0.f, 0.f, 0.f, 0.f};
                acc = mfma16(k0, qf0, acc);
                acc = mfma16(k1, qf1, acc);
                s[t] = acc;
            }

            float a[16];
            #pragma unroll
            for (int t = 0; t < 4; ++t)
                #pragma unroll
                for (int r = 0; r < 4; ++r) a[4 * t + r] = s[t][r];

            if (kv0 + 63 > q0w) {                         // wave-uniform causal branch
                const int qg = q0w + r16;
                #pragma unroll
                for (int t = 0; t < 4; ++t)
                    #pragma unroll
                    for (int r = 0; r < 4; ++r)
                        if (kv0 + 16 * t + 4 * g16 + r > qg) a[4 * t + r] = -1.0e30f;
            }

            float mx = a[0];
            #pragma unroll
            for (int j = 1; j < 16; ++j) mx = fmaxf(mx, a[j]);
            mx = fmaxf(mx, __shfl_xor(mx, 16));
            mx = fmaxf(mx, __shfl_xor(mx, 32));

            const float mn = fmaxf(mreg, mx);
            float p[16], rs = 0.0f;
            #pragma unroll
            for (int j = 0; j < 16; ++j) { p[j] = exp2f(a[j] - mn); rs += p[j]; }
            rs += __shfl_xor(rs, 16);
            rs += __shfl_xor(rs, 32);

            if (__all(mx <= mreg)) {                      // defer-max: no rescale
                lreg += rs;
            } else {
                const float al = exp2f(mreg - mn);
                lreg = lreg * al + rs;
                mreg = mn;
                #pragma unroll
                for (int t = 0; t < 4; ++t)
                    #pragma unroll
                    for (int r = 0; r < 4; ++r) o[t][r] *= al;
            }

            bf16x8 pf0, pf1;
            #pragma unroll
            for (int j = 0; j < 8; ++j) { pf0[j] = (__bf16)p[j]; pf1[j] = (__bf16)p[8 + j]; }

            // PV: permuted-V layout -> one b128 per (t, half32)
            #pragma unroll
            for (int t = 0; t < 4; ++t) {
                const int row = 16 * t + r16;
                const int sw  = row & 7;
                const bf16x8 v0 = ldf(&V[row * 64 + ((g16 ^ sw) * 8)]);
                const bf16x8 v1 = ldf(&V[row * 64 + (((4 + g16) ^ sw) * 8)]);
                o[t] = mfma16(v0, pf0, o[t]);
                o[t] = mfma16(v1, pf1, o[t]);
            }

            if (it + 1 < nt) {
                if (pf) { asm volatile("s_waitcnt vmcnt(4)" ::: "memory"); }   // retire it+1
                else    { asm volatile("s_waitcnt vmcnt(0)" ::: "memory"); }
                __builtin_amdgcn_s_barrier();
            }
            cur = (cur == 2) ? 0 : cur + 1;
            nx2 = (nx2 == 2) ? 0 : nx2 + 1;
        }

        const float inv = 1.0f / lreg;
        u16* op = Ob + (seqb + q0w + r16) * 1024 + h * 64 + 4 * g16;
        #pragma unroll
        for (int t = 0; t < 4; ++t) {
            U4 st;
            #pragma unroll
            for (int r = 0; r < 4; ++r) st.v[r] = f2bf(o[t][r] * inv);
            *(U4*)(op + 16 * t) = st;
        }
    }
}

// ---------- launch ----------
extern "C" void kernel_launch(void* const* d_in, const int* in_sizes, int n_in,
                              void* d_out, int out_size, void* d_ws, size_t ws_size,
                              hipStream_t stream) {
    (void)in_sizes; (void)n_in; (void)out_size; (void)ws_size;
    constexpr int C = 1024, FF = 4096, M = 2 * 2048;   // B*T = 4096
    constexpr size_t MB = 1024 * 1024;

    const float* x      = (const float*)d_in[0];
    const float* ln1_w  = (const float*)d_in[1];
    const float* ln1_b  = (const float*)d_in[2];
    const float* qkv_w  = (const float*)d_in[3];
    const float* atto_w = (const float*)d_in[4];
    const float* ln2_w  = (const float*)d_in[5];
    const float* ln2_b  = (const float*)d_in[6];
    const float* mlpi_w = (const float*)d_in[7];
    const float* mlpg_w = (const float*)d_in[8];
    const float* mlpo_w = (const float*)d_in[9];
    float* out = (float*)d_out;

    char* ws = (char*)d_ws;
    size_t off = 0;
    auto alloc = [&](size_t bytes) {
        char* p = ws + off;
        off += (bytes + 255) & ~(size_t)255;
        return p;
    };
    u16*   wq   = (u16*)  alloc((size_t)3 * C * C * 2);   // qkv_w bf16 (Q,K rows then V)
    u16*   wo   = (u16*)  alloc((size_t)C * C * 2);
    u16*   wig  = (u16*)  alloc((size_t)2 * FF * C * 2);  // interleaved wi/wg [8192][1024]
    u16*   wm   = (u16*)  alloc((size_t)C * FF * 2);
    float* x1   = (float*)alloc((size_t)M * C * 4);
    u16*   h2   = (u16*)  alloc((size_t)M * C * 2);
    u16*   ab   = (u16*)  alloc((size_t)M * FF * 2);
    // region R (64 MB): attn-phase buffers; later reused for mlpo partials
    char*  R    = alloc(64 * MB);
    u16*   h1   = (u16*)R;                 //  8 MB
    u16*   qk_b = (u16*)(R + 8 * MB);      // 16 MB  [4096][2048] Q|K
    u16*   vt_b = (u16*)(R + 24 * MB);     //  8 MB  [1024][4096] V^T (PV-permuted)
    u16*   Ob   = (u16*)(R + 32 * MB);     //  8 MB
    u16*   aoP  = (u16*)(R + 40 * MB);     // 16 MB  attn_out bf16 partials (2 planes)
    u16*   pscr = (u16*)R;                 // 32 MB  mlpo bf16 partials (4 planes) — after attn

    // all weight casts (one kernel)
    cast_all_k<<<8192, 256, 0, stream>>>(qkv_w, atto_w, mlpo_w, mlpi_w, mlpg_w,
                                         wq, wo, wm, wig);

    // attention branch
    ln_fwd_k<<<M, 256, 0, stream>>>(x, ln1_w, ln1_b, h1);
    gemm_qkvt_k<<<768, 256, 0, stream>>>(h1, wq, qk_b, vt_b);
    attn_fwd_k<<<512, 256, 0, stream>>>(qk_b, vt_b, Ob);
    // attn_out: split-K=2 bf16 partials (512 blocks = 2/CU)
    gemm_btsplit_k<<<dim3(C / 128, M / 128, 2), 256, 0, stream>>>(
        Ob, wo, aoP, C, C, C / 2, M * C);
    // fused residual+LN2: x1 = x + p0 + p1 ; h2 = LN(x1)
    ln_resid_k<<<M, 256, 0, stream>>>(x, aoP, ln2_w, ln2_b, x1, h2, M * C);

    // MLP branch (v3 128-KiB kernels — best measured)
    gemm256_k<2><<<dim3((2 * FF / 256) * (M / 256), 1, 1), 512, 0, stream>>>(
        h2, wig, ab, C, C, C, 2 * FF / 256, 8, FF, 0);
    gemm256_k<1><<<dim3((C / 256) * (M / 256), 1, 4), 512, 0, stream>>>(
        ab, wm, pscr, FF, FF, FF / 4, C / 256, 4, C, M * C);
    addreduce4_k<<<2048, 256, 0, stream>>>(x1, pscr, out, M * C / 4, M * C);
}

// Round 14
// 243.860 us; speedup vs baseline: 1.0865x; 1.0237x over previous
//
#include <hip/hip_runtime.h>
#include <cstdint>

// ---------- types & helpers ----------
typedef unsigned short u16;
typedef __bf16 bf16x8 __attribute__((ext_vector_type(8)));
typedef float  f32x4  __attribute__((ext_vector_type(4)));

struct alignas(16) F4 { float v[4]; };
struct alignas(8)  U4 { u16 v[4]; };
struct alignas(16) U8 { u16 v[8]; };

__device__ __forceinline__ u16 f2bf(float f) {
    union { float f; unsigned int u; } x; x.f = f;
    unsigned int r = x.u + 0x7fffu + ((x.u >> 16) & 1u);   // RNE
    return (u16)(r >> 16);
}
__device__ __forceinline__ float bf2f(u16 u) {
    union { unsigned int u; float f; } x; x.u = ((unsigned int)u) << 16;
    return x.f;
}
__device__ __forceinline__ f32x4 mfma16(bf16x8 a, bf16x8 b, f32x4 c) {
    return __builtin_amdgcn_mfma_f32_16x16x32_bf16(a, b, c, 0, 0, 0);
}
__device__ __forceinline__ bf16x8 ldf(const u16* p) { return *(const bf16x8*)p; }
// async global->LDS, 16B per lane, dest = wave-uniform base + lane*16
__device__ __forceinline__ void gload_lds16(const void* g, void* l) {
    auto* gp = reinterpret_cast<const __attribute__((address_space(1))) unsigned int*>(
        reinterpret_cast<uintptr_t>(g));
    auto* lp = reinterpret_cast<__attribute__((address_space(3))) unsigned int*>(
        reinterpret_cast<uintptr_t>(l));
    __builtin_amdgcn_global_load_lds(gp, lp, 16, 0, 0);
}

// ---------- ALL weight casts in one kernel ----------
__global__ __launch_bounds__(256) void cast_all_k(const float* __restrict__ qkvw,
                                                  const float* __restrict__ attow,
                                                  const float* __restrict__ mlpow,
                                                  const float* __restrict__ wi,
                                                  const float* __restrict__ wg,
                                                  u16* __restrict__ wq,
                                                  u16* __restrict__ wo,
                                                  u16* __restrict__ wm,
                                                  u16* __restrict__ wig) {
    constexpr int N1 = 3 * 1024 * 1024 / 8;            // wq units-of-8
    constexpr int N2 = N1 + 1024 * 1024 / 8;           // +wo
    constexpr int N3 = N2 + 1024 * 4096 / 8;           // +wm
    const int i = blockIdx.x * 256 + threadIdx.x;
    const float* src; u16* dst;
    if (i < N1)      { src = qkvw  + (size_t)i * 8;        dst = wq + (size_t)i * 8; }
    else if (i < N2) { const int j = i - N1; src = attow + (size_t)j * 8; dst = wo + (size_t)j * 8; }
    else if (i < N3) { const int j = i - N2; src = mlpow + (size_t)j * 8; dst = wm + (size_t)j * 8; }
    else {
        const int j = i - N3;
        const int w = j >> 7, c8 = (j & 127) * 8;
        const int f = ((w >> 6) << 5) | (w & 31);
        src = ((w & 32) ? wg : wi) + (size_t)f * 1024 + c8;
        dst = wig + (size_t)w * 1024 + c8;
    }
    F4 a = *(const F4*)src;
    F4 b = *(const F4*)(src + 4);
    U8 o;
    #pragma unroll
    for (int j = 0; j < 4; ++j) { o.v[j] = f2bf(a.v[j]); o.v[4 + j] = f2bf(b.v[j]); }
    *(U8*)dst = o;
}

// ---------- LayerNorm (C=1024), f32 in -> bf16 out ----------
__global__ __launch_bounds__(256) void ln_fwd_k(const float* __restrict__ x,
                                                const float* __restrict__ w,
                                                const float* __restrict__ b,
                                                u16* __restrict__ h) {
    const int row = blockIdx.x, tid = threadIdx.x;
    const float* xr = x + (size_t)row * 1024;
    F4 v = *(const F4*)(xr + tid * 4);
    float s  = v.v[0] + v.v[1] + v.v[2] + v.v[3];
    float ss = v.v[0]*v.v[0] + v.v[1]*v.v[1] + v.v[2]*v.v[2] + v.v[3]*v.v[3];
    #pragma unroll
    for (int o = 32; o > 0; o >>= 1) { s += __shfl_down(s, o); ss += __shfl_down(ss, o); }
    __shared__ float red[8];
    const int wave = tid >> 6, lane = tid & 63;
    if (lane == 0) { red[wave] = s; red[4 + wave] = ss; }
    __syncthreads();
    s  = red[0] + red[1] + red[2] + red[3];
    ss = red[4] + red[5] + red[6] + red[7];
    const float mu   = s * (1.0f / 1024.0f);
    const float var  = ss * (1.0f / 1024.0f) - mu * mu;
    const float rstd = rsqrtf(var + 1e-5f);
    U4 o;
    #pragma unroll
    for (int j = 0; j < 4; ++j)
        o.v[j] = f2bf((v.v[j] - mu) * rstd * w[tid * 4 + j] + b[tid * 4 + j]);
    *(U4*)(h + (size_t)row * 1024 + tid * 4) = o;
}

// ---------- fused residual + LN2: x1 = x + p0 + p1 (bf16 planes); h2 = LN(x1) ----------
__global__ __launch_bounds__(256) void ln_resid_k(const float* __restrict__ x,
                                                  const u16* __restrict__ p,
                                                  const float* __restrict__ w,
                                                  const float* __restrict__ b,
                                                  float* __restrict__ x1,
                                                  u16* __restrict__ h,
                                                  int planeEls) {
    const int row = blockIdx.x, tid = threadIdx.x;
    const size_t base = (size_t)row * 1024 + tid * 4;
    F4 xv = *(const F4*)(x + base);
    U4 q0 = *(const U4*)(p + base);
    U4 q1 = *(const U4*)(p + (size_t)planeEls + base);
    F4 sv;
    #pragma unroll
    for (int j = 0; j < 4; ++j) sv.v[j] = xv.v[j] + bf2f(q0.v[j]) + bf2f(q1.v[j]);
    *(F4*)(x1 + base) = sv;
    float s  = sv.v[0] + sv.v[1] + sv.v[2] + sv.v[3];
    float ss = sv.v[0]*sv.v[0] + sv.v[1]*sv.v[1] + sv.v[2]*sv.v[2] + sv.v[3]*sv.v[3];
    #pragma unroll
    for (int o = 32; o > 0; o >>= 1) { s += __shfl_down(s, o); ss += __shfl_down(ss, o); }
    __shared__ float red[8];
    const int wave = tid >> 6, lane = tid & 63;
    if (lane == 0) { red[wave] = s; red[4 + wave] = ss; }
    __syncthreads();
    s  = red[0] + red[1] + red[2] + red[3];
    ss = red[4] + red[5] + red[6] + red[7];
    const float mu   = s * (1.0f / 1024.0f);
    const float var  = ss * (1.0f / 1024.0f) - mu * mu;
    const float rstd = rsqrtf(var + 1e-5f);
    U4 o;
    #pragma unroll
    for (int j = 0; j < 4; ++j)
        o.v[j] = f2bf((sv.v[j] - mu) * rstd * w[tid * 4 + j] + b[tid * 4 + j]);
    *(U4*)(h + base) = o;
}

// ---------- combined qk + vt GEMM (one dispatch, 768 blocks) ----------
__global__ __launch_bounds__(256) void gemm_qkvt_k(const u16* __restrict__ h1,
                                                   const u16* __restrict__ wq,
                                                   u16* __restrict__ qk_b,
                                                   u16* __restrict__ vt_b) {
    __shared__ alignas(16) u16 Alds[128 * 32];
    __shared__ alignas(16) u16 Blds[128 * 32];
    const int tid  = threadIdx.x;
    const int lane = tid & 63, wave = tid >> 6;
    const int wr = wave >> 1, wc = wave & 1;
    const int r16 = lane & 15, g16 = lane >> 4;

    const u16* A; const u16* Bm; u16* Cout; int bn, bm, N, role;
    const int bid = blockIdx.x;
    if (bid < 512) { A = h1; Bm = wq; Cout = qk_b; N = 2048; bn = bid & 15; bm = bid >> 4; role = 0; }
    else {
        const int id = bid - 512;
        A = wq + (size_t)2 * 1024 * 1024;   // wv rows
        Bm = h1; Cout = vt_b; N = 4096; bn = id & 31; bm = id >> 5; role = 1;
    }
    constexpr int K = 1024;

    const int srow = lane >> 2;
    const int scol = (lane & 3) * 8;

    f32x4 acc[4][4] = {};

    for (int k0 = 0; k0 < K; k0 += 32) {
        #pragma unroll
        for (int c = 0; c < 2; ++c) {
            const int ch = wave * 2 + c;
            const u16* ga = A  + ((size_t)bm * 128 + ch * 16 + srow) * K + k0 + scol;
            gload_lds16(ga, &Alds[ch * 512]);
            const u16* gb = Bm + ((size_t)bn * 128 + ch * 16 + srow) * K + k0 + scol;
            gload_lds16(gb, &Blds[ch * 512]);
        }
        __syncthreads();
        bf16x8 af[4], bfr[4];
        #pragma unroll
        for (int m = 0; m < 4; ++m)
            af[m] = ldf(&Alds[(wr * 64 + m * 16 + r16) * 32 + g16 * 8]);
        #pragma unroll
        for (int n = 0; n < 4; ++n)
            bfr[n] = ldf(&Blds[(wc * 64 + n * 16 + r16) * 32 + g16 * 8]);
        #pragma unroll
        for (int m = 0; m < 4; ++m)
            #pragma unroll
            for (int n = 0; n < 4; ++n)
                acc[m][n] = mfma16(af[m], bfr[n], acc[m][n]);
        __syncthreads();
    }

    constexpr float SCQ = 0.125f * 1.44269504088896341f;
    #pragma unroll
    for (int m = 0; m < 4; ++m)
        #pragma unroll
        for (int n = 0; n < 4; ++n)
            #pragma unroll
            for (int r = 0; r < 4; ++r) {
                const int row = bm * 128 + wr * 64 + m * 16 + g16 * 4 + r;
                int col = bn * 128 + wc * 64 + n * 16 + r16;
                float v = acc[m][n][r];
                if (role == 0) {
                    if (col < 1024) v *= SCQ;                 // Q pre-scale
                } else {
                    const int c5 = col & 31;                   // PV permutation
                    const int pos = 8 * ((c5 & 15) >> 2) + 4 * (c5 >> 4) + (c5 & 3);
                    col = (col & ~31) | pos;
                }
                Cout[(size_t)row * N + col] = f2bf(v);
            }
}

// ---------- 128x128 GEMM, split-K bf16 partial planes (attn_out) ----------
__global__ __launch_bounds__(256) void gemm_btsplit_k(const u16* __restrict__ A,
                                                      const u16* __restrict__ Bm,
                                                      u16* __restrict__ P,
                                                      int N, int K, int kchunk,
                                                      int planeEls) {
    __shared__ alignas(16) u16 Alds[128 * 32];
    __shared__ alignas(16) u16 Blds[128 * 32];
    const int tid  = threadIdx.x;
    const int lane = tid & 63, wave = tid >> 6;
    const int wr = wave >> 1, wc = wave & 1;
    const int r16 = lane & 15, g16 = lane >> 4;
    const int bn = blockIdx.x, bm = blockIdx.y;
    const int kBeg = blockIdx.z * kchunk;

    const int srow = lane >> 2;
    const int scol = (lane & 3) * 8;

    f32x4 acc[4][4] = {};

    for (int k0 = kBeg; k0 < kBeg + kchunk; k0 += 32) {
        #pragma unroll
        for (int c = 0; c < 2; ++c) {
            const int ch = wave * 2 + c;
            const u16* ga = A  + ((size_t)bm * 128 + ch * 16 + srow) * K + k0 + scol;
            gload_lds16(ga, &Alds[ch * 512]);
            const u16* gb = Bm + ((size_t)bn * 128 + ch * 16 + srow) * K + k0 + scol;
            gload_lds16(gb, &Blds[ch * 512]);
        }
        __syncthreads();
        bf16x8 af[4], bfr[4];
        #pragma unroll
        for (int m = 0; m < 4; ++m)
            af[m] = ldf(&Alds[(wr * 64 + m * 16 + r16) * 32 + g16 * 8]);
        #pragma unroll
        for (int n = 0; n < 4; ++n)
            bfr[n] = ldf(&Blds[(wc * 64 + n * 16 + r16) * 32 + g16 * 8]);
        #pragma unroll
        for (int m = 0; m < 4; ++m)
            #pragma unroll
            for (int n = 0; n < 4; ++n)
                acc[m][n] = mfma16(af[m], bfr[n], acc[m][n]);
        __syncthreads();
    }

    u16* Pp = P + (size_t)blockIdx.z * planeEls;
    #pragma unroll
    for (int m = 0; m < 4; ++m)
        #pragma unroll
        for (int n = 0; n < 4; ++n)
            #pragma unroll
            for (int r = 0; r < 4; ++r) {
                const int row = bm * 128 + wr * 64 + m * 16 + g16 * 4 + r;
                const int col = bn * 128 + wc * 64 + n * 16 + r16;
                Pp[(size_t)row * N + col] = f2bf(acc[m][n][r]);
            }
}

// ---------- 256x256 pipelined GEMM v3 (frag-prefetch; best measured) ----------
template <int EPI>
__global__ __launch_bounds__(512, 2)
void gemm256_k(const u16* __restrict__ A, const u16* __restrict__ Bm,
               void* __restrict__ Cout, int lda, int ldb, int kLen,
               int nx, int bnCh, int outLd, int planeEls) {
    __shared__ alignas(16) u16 lds[2][2][2][128 * 64];

    const int tid  = threadIdx.x;
    const int wave = tid >> 6, lane = tid & 63;
    const int wm = wave >> 2, wn = wave & 3;
    const int r16 = lane & 15, g16 = lane >> 4;

    const int cpx = gridDim.x >> 3;
    const int xcd = blockIdx.x & 7, loc = blockIdx.x >> 3;
    const int mCh = cpx / bnCh;
    const int cpr = nx / bnCh;
    const int bm = (xcd / cpr) * mCh + loc / bnCh;
    const int bn = (xcd % cpr) * bnCh + loc % bnCh;
    const int kBeg = blockIdx.z * kLen;
    const int NT = kLen >> 6;

    const int csw = ((lane & 7) ^ (lane >> 3)) * 8;
    const u16* aU = A  + (size_t)(bm * 256) * lda + kBeg;
    const u16* bU = Bm + (size_t)(bn * 256) * ldb + kBeg;
    int aOff[2][2], bOff[2][2];
    #pragma unroll
    for (int h = 0; h < 2; ++h)
        #pragma unroll
        for (int i = 0; i < 2; ++i) {
            const int wr = wave * 16 + (lane >> 3) + i * 8;
            const int ar = (wr >> 6) * 128 + h * 64 + (wr & 63);
            const int br = (wr >> 5) * 64 + h * 32 + (wr & 31);
            aOff[h][i] = ar * lda + csw;
            bOff[h][i] = br * ldb + csw;
        }

    auto stA = [&](int kt, int h) {
        u16* d = &lds[kt & 1][0][h][wave * 1024];
        gload_lds16(aU + aOff[h][0] + kt * 64, d);
        gload_lds16(aU + aOff[h][1] + kt * 64, d + 512);
    };
    auto stB = [&](int kt, int h) {
        u16* d = &lds[kt & 1][1][h][wave * 1024];
        gload_lds16(bU + bOff[h][0] + kt * 64, d);
        gload_lds16(bU + bOff[h][1] + kt * 64, d + 512);
    };

    int offA[4][2], offB[2][2];
    #pragma unroll
    for (int m = 0; m < 4; ++m)
        #pragma unroll
        for (int ks = 0; ks < 2; ++ks)
            offA[m][ks] = (wm * 64 + m * 16 + r16) * 64 + (((ks * 4 + g16) ^ (r16 & 7)) * 8);
    #pragma unroll
    for (int n = 0; n < 2; ++n)
        #pragma unroll
        for (int ks = 0; ks < 2; ++ks)
            offB[n][ks] = (wn * 32 + n * 16 + r16) * 64 + (((ks * 4 + g16) ^ (r16 & 7)) * 8);

    f32x4 acc[8][4] = {};
    bf16x8 af0[4][2], af1[4][2], b0v[2][2], b1v[2][2];

    auto rdAF0 = [&](int buf) {
        const u16* P = &lds[buf][0][0][0];
        #pragma unroll
        for (int m = 0; m < 4; ++m) { af0[m][0] = ldf(P + offA[m][0]); af0[m][1] = ldf(P + offA[m][1]); }
    };
    auto rdAF1 = [&](int buf) {
        const u16* P = &lds[buf][0][1][0];
        #pragma unroll
        for (int m = 0; m < 4; ++m) { af1[m][0] = ldf(P + offA[m][0]); af1[m][1] = ldf(P + offA[m][1]); }
    };
    auto rdB0 = [&](int buf) {
        const u16* P = &lds[buf][1][0][0];
        #pragma unroll
        for (int n = 0; n < 2; ++n) { b0v[n][0] = ldf(P + offB[n][0]); b0v[n][1] = ldf(P + offB[n][1]); }
    };
    auto rdB1 = [&](int buf) {
        const u16* P = &lds[buf][1][1][0];
        #pragma unroll
        for (int n = 0; n < 2; ++n) { b1v[n][0] = ldf(P + offB[n][0]); b1v[n][1] = ldf(P + offB[n][1]); }
    };

    stA(0, 0); stB(0, 0); stB(0, 1); stA(0, 1);
    stA(1, 0); stB(1, 0); stB(1, 1); stA(1, 1);
    asm volatile("s_waitcnt vmcnt(8)" ::: "memory");
    __builtin_amdgcn_s_barrier();
    rdAF0(0); rdB0(0); rdB1(0); rdAF1(0);

    for (int kt = 0; kt < NT; ++kt) {
        const bool pf = (kt + 2 < NT);
        const int nb = (kt + 1) & 1;

        __builtin_amdgcn_s_setprio(1);
        #pragma unroll
        for (int m = 0; m < 4; ++m)
            #pragma unroll
            for (int n = 0; n < 2; ++n) {
                acc[m][n] = mfma16(af0[m][0], b0v[n][0], acc[m][n]);
                acc[m][n] = mfma16(af0[m][1], b0v[n][1], acc[m][n]);
            }
        __builtin_amdgcn_s_setprio(0);
        __builtin_amdgcn_s_barrier();

        if (pf) { stA(kt + 2, 0); stB(kt + 2, 0); }
        __builtin_amdgcn_s_setprio(1);
        #pragma unroll
        for (int m = 0; m < 4; ++m)
            #pragma unroll
            for (int n = 0; n < 2; ++n) {
                acc[m][n + 2] = mfma16(af0[m][0], b1v[n][0], acc[m][n + 2]);
                acc[m][n + 2] = mfma16(af0[m][1], b1v[n][1], acc[m][n + 2]);
            }
        __builtin_amdgcn_s_setprio(0);
        __builtin_amdgcn_s_barrier();

        if (pf) stB(kt + 2, 1);
        __builtin_amdgcn_s_setprio(1);
        #pragma unroll
        for (int m = 0; m < 4; ++m)
            #pragma unroll
            for (int n = 0; n < 2; ++n) {
                acc[m + 4][n] = mfma16(af1[m][0], b0v[n][0], acc[m + 4][n]);
                acc[m + 4][n] = mfma16(af1[m][1], b0v[n][1], acc[m + 4][n]);
            }
        __builtin_amdgcn_s_setprio(0);
        __builtin_amdgcn_s_barrier();

        if (pf) stA(kt + 2, 1);
        if (pf)               { asm volatile("s_waitcnt vmcnt(8)" ::: "memory"); }
        else if (kt + 1 < NT) { asm volatile("s_waitcnt vmcnt(0)" ::: "memory"); }
        if (kt + 1 < NT) {
            __builtin_amdgcn_s_barrier();
            rdAF0(nb); rdB0(nb);
        }
        __builtin_amdgcn_s_setprio(1);
        #pragma unroll
        for (int m = 0; m < 4; ++m)
            #pragma unroll
            for (int n = 0; n < 2; ++n) {
                acc[m + 4][n + 2] = mfma16(af1[m][0], b1v[n][0], acc[m + 4][n + 2]);
                acc[m + 4][n + 2] = mfma16(af1[m][1], b1v[n][1], acc[m + 4][n + 2]);
            }
        __builtin_amdgcn_s_setprio(0);
        if (kt + 1 < NT) { rdB1(nb); rdAF1(nb); }
    }

    if constexpr (EPI == 1) {
        u16* P = (u16*)Cout + (size_t)blockIdx.z * planeEls;
        #pragma unroll
        for (int m = 0; m < 8; ++m)
            #pragma unroll
            for (int n = 0; n < 4; ++n)
                #pragma unroll
                for (int r = 0; r < 4; ++r) {
                    const int row = bm * 256 + wm * 128 + m * 16 + g16 * 4 + r;
                    const int col = bn * 256 + wn * 64 + n * 16 + r16;
                    P[(size_t)row * outLd + col] = f2bf(acc[m][n][r]);
                }
    } else {
        (void)planeEls;
        u16* O = (u16*)Cout;
        #pragma unroll
        for (int m = 0; m < 8; ++m)
            #pragma unroll
            for (int n = 0; n < 2; ++n)
                #pragma unroll
                for (int r = 0; r < 4; ++r) {
                    const int row = bm * 256 + wm * 128 + m * 16 + g16 * 4 + r;
                    const int col = (bn * 4 + wn) * 32 + n * 16 + r16;
                    const float vi = acc[m][n][r];
                    const float vg = acc[m][n + 2][r];
                    const float sl = vi / (1.0f + __expf(-vi));
                    O[(size_t)row * outLd + col] = f2bf(sl * vg);
                }
    }
}

// ---------- split-K reduce: out = resid + sum of 4 bf16 planes ----------
__global__ __launch_bounds__(256) void addreduce4_k(const float* __restrict__ resid,
                                                    const u16* __restrict__ p,
                                                    float* __restrict__ out,
                                                    int n4, int planeEls) {
    for (int i = blockIdx.x * 256 + threadIdx.x; i < n4; i += gridDim.x * 256) {
        F4 a = *(const F4*)(resid + (size_t)i * 4);
        U4 q0 = *(const U4*)(p + (size_t)i * 4);
        U4 q1 = *(const U4*)(p + (size_t)planeEls + (size_t)i * 4);
        U4 q2 = *(const U4*)(p + (size_t)2 * planeEls + (size_t)i * 4);
        U4 q3 = *(const U4*)(p + (size_t)3 * planeEls + (size_t)i * 4);
        F4 o;
        #pragma unroll
        for (int j = 0; j < 4; ++j)
            o.v[j] = a.v[j] + bf2f(q0.v[j]) + bf2f(q1.v[j]) + bf2f(q2.v[j]) + bf2f(q3.v[j]);
        *(F4*)(out + (size_t)i * 4) = o;
    }
}

// ---------- flash attention v4: paired q-tiles, permuted-V b128 PV,
// log2-domain softmax, defer-max rescale skip (best measured: round 11) ----------
__global__ __launch_bounds__(256) void attn_fwd_k(const u16* __restrict__ qk,
                                                  const u16* __restrict__ vt,
                                                  u16* __restrict__ Ob) {
    __shared__ alignas(16) u16 Klds[2][64 * 64];
    __shared__ alignas(16) u16 Vlds[2][64 * 64];

    const int tid  = threadIdx.x;
    const int wave = tid >> 6, lane = tid & 63;
    const int r16  = lane & 15, g16 = lane >> 4;

    const int bh = blockIdx.x >> 4, pi = blockIdx.x & 15;
    const int h  = bh & 15, b = bh >> 4;
    const size_t seqb = (size_t)b * 2048;

    const u16* kbase = qk + seqb * 2048 + 1024 + (size_t)h * 64;
    const u16* vbase = vt + (size_t)(h * 64) * 4096 + seqb;

    const int srow  = tid >> 3;                           // 0..31
    const int scol8 = ((tid & 7) ^ (srow & 7)) * 8;
    const u16* ksrc = kbase + (size_t)srow * 2048 + scol8;
    const u16* vsrc = vbase + (size_t)srow * 4096 + scol8;

    auto stage = [&](int bufi, int kv0) {
        const u16* kp = ksrc + (size_t)kv0 * 2048;
        const u16* vp = vsrc + kv0;
        u16* kd = &Klds[bufi][wave * 512];
        u16* vd = &Vlds[bufi][wave * 512];
        gload_lds16(kp, kd);
        gload_lds16(kp + (size_t)32 * 2048, kd + 2048);
        gload_lds16(vp, vd);
        gload_lds16(vp + (size_t)32 * 4096, vd + 2048);
    };

    #pragma unroll 1
    for (int half = 0; half < 2; ++half) {
        const int qb  = half ? pi : (31 - pi);            // long tile first
        const int q0w = qb * 64 + wave * 16;

        const u16* qp = qk + (seqb + q0w + r16) * 2048 + h * 64 + g16 * 8;
        const bf16x8 qf0 = *(const bf16x8*)qp;            // Q pre-scaled by 0.125*log2e
        const bf16x8 qf1 = *(const bf16x8*)(qp + 32);

        f32x4 o[4] = {};
        float mreg = -3.0e38f, lreg = 0.0f;
        const int nt = qb + 1;

        if (half) __syncthreads();                        // protect LDS vs prev half
        stage(0, 0);
        asm volatile("s_waitcnt vmcnt(0)" ::: "memory");
        __builtin_amdgcn_s_barrier();

        for (int it = 0; it < nt; ++it) {
            const int kv0 = it * 64;
            const int cur = it & 1;
            if (it + 1 < nt) stage(cur ^ 1, kv0 + 64);

            const u16* K = Klds[cur];
            const u16* V = Vlds[cur];

            f32x4 s[4];
            #pragma unroll
            for (int t = 0; t < 4; ++t) {
                const int row = 16 * t + r16;
                const int sw  = row & 7;
                const bf16x8 k0 = ldf(&K[row * 64 + ((g16 ^ sw) * 8)]);
                const bf16x8 k1 = ldf(&K[row * 64 + (((g16 + 4) ^ sw) * 8)]);
                f32x4 acc = {0.f, 0.f, 0.f, 0.f};
                acc = mfma16(k0, qf0, acc);
                acc = mfma16(k1, qf1, acc);
                s[t] = acc;
            }

            float a[16];
            #pragma unroll
            for (int t = 0; t < 4; ++t)
                #pragma unroll
                for (int r = 0; r < 4; ++r) a[4 * t + r] = s[t][r];

            if (kv0 + 63 > q0w) {                         // wave-uniform causal branch
                const int qg = q0w + r16;
                #pragma unroll
                for (int t = 0; t < 4; ++t)
                    #pragma unroll
                    for (int r = 0; r < 4; ++r)
                        if (kv0 + 16 * t + 4 * g16 + r > qg) a[4 * t + r] = -1.0e30f;
            }

            float mx = a[0];
            #pragma unroll
            for (int j = 1; j < 16; ++j) mx = fmaxf(mx, a[j]);
            mx = fmaxf(mx, __shfl_xor(mx, 16));
            mx = fmaxf(mx, __shfl_xor(mx, 32));

            const float mn = fmaxf(mreg, mx);
            float p[16], rs = 0.0f;
            #pragma unroll
            for (int j = 0; j < 16; ++j) { p[j] = exp2f(a[j] - mn); rs += p[j]; }
            rs += __shfl_xor(rs, 16);
            rs += __shfl_xor(rs, 32);

            if (__all(mx <= mreg)) {                      // defer-max: no rescale
                lreg += rs;
            } else {
                const float al = exp2f(mreg - mn);
                lreg = lreg * al + rs;
                mreg = mn;
                #pragma unroll
                for (int t = 0; t < 4; ++t)
                    #pragma unroll
                    for (int r = 0; r < 4; ++r) o[t][r] *= al;
            }

            bf16x8 pf0, pf1;
            #pragma unroll
            for (int j = 0; j < 8; ++j) { pf0[j] = (__bf16)p[j]; pf1[j] = (__bf16)p[8 + j]; }

            // PV: permuted-V layout -> one b128 per (t, half32)
            #pragma unroll
            for (int t = 0; t < 4; ++t) {
                const int row = 16 * t + r16;
                const int sw  = row & 7;
                const bf16x8 v0 = ldf(&V[row * 64 + ((g16 ^ sw) * 8)]);
                const bf16x8 v1 = ldf(&V[row * 64 + (((4 + g16) ^ sw) * 8)]);
                o[t] = mfma16(v0, pf0, o[t]);
                o[t] = mfma16(v1, pf1, o[t]);
            }

            if (it + 1 < nt) {
                asm volatile("s_waitcnt vmcnt(0)" ::: "memory");
                __builtin_amdgcn_s_barrier();
            }
        }

        const float inv = 1.0f / lreg;
        u16* op = Ob + (seqb + q0w + r16) * 1024 + h * 64 + 4 * g16;
        #pragma unroll
        for (int t = 0; t < 4; ++t) {
            U4 st;
            #pragma unroll
            for (int r = 0; r < 4; ++r) st.v[r] = f2bf(o[t][r] * inv);
            *(U4*)(op + 16 * t) = st;
        }
    }
}

// ---------- launch ----------
extern "C" void kernel_launch(void* const* d_in, const int* in_sizes, int n_in,
                              void* d_out, int out_size, void* d_ws, size_t ws_size,
                              hipStream_t stream) {
    (void)in_sizes; (void)n_in; (void)out_size; (void)ws_size;
    constexpr int C = 1024, FF = 4096, M = 2 * 2048;   // B*T = 4096
    constexpr size_t MB = 1024 * 1024;

    const float* x      = (const float*)d_in[0];
    const float* ln1_w  = (const float*)d_in[1];
    const float* ln1_b  = (const float*)d_in[2];
    const float* qkv_w  = (const float*)d_in[3];
    const float* atto_w = (const float*)d_in[4];
    const float* ln2_w  = (const float*)d_in[5];
    const float* ln2_b  = (const float*)d_in[6];
    const float* mlpi_w = (const float*)d_in[7];
    const float* mlpg_w = (const float*)d_in[8];
    const float* mlpo_w = (const float*)d_in[9];
    float* out = (float*)d_out;

    char* ws = (char*)d_ws;
    size_t off = 0;
    auto alloc = [&](size_t bytes) {
        char* p = ws + off;
        off += (bytes + 255) & ~(size_t)255;
        return p;
    };
    u16*   wq   = (u16*)  alloc((size_t)3 * C * C * 2);   // qkv_w bf16 (Q,K rows then V)
    u16*   wo   = (u16*)  alloc((size_t)C * C * 2);
    u16*   wig  = (u16*)  alloc((size_t)2 * FF * C * 2);  // interleaved wi/wg [8192][1024]
    u16*   wm   = (u16*)  alloc((size_t)C * FF * 2);
    float* x1   = (float*)alloc((size_t)M * C * 4);
    u16*   h2   = (u16*)  alloc((size_t)M * C * 2);
    u16*   ab   = (u16*)  alloc((size_t)M * FF * 2);
    // region R (64 MB): attn-phase buffers; later reused for mlpo partials
    char*  R    = alloc(64 * MB);
    u16*   h1   = (u16*)R;                 //  8 MB
    u16*   qk_b = (u16*)(R + 8 * MB);      // 16 MB  [4096][2048] Q|K
    u16*   vt_b = (u16*)(R + 24 * MB);     //  8 MB  [1024][4096] V^T (PV-permuted)
    u16*   Ob   = (u16*)(R + 32 * MB);     //  8 MB
    u16*   aoP  = (u16*)(R + 40 * MB);     // 16 MB  attn_out bf16 partials (2 planes)
    u16*   pscr = (u16*)R;                 // 32 MB  mlpo bf16 partials (4 planes) — after attn

    // all weight casts (one kernel)
    cast_all_k<<<8192, 256, 0, stream>>>(qkv_w, atto_w, mlpo_w, mlpi_w, mlpg_w,
                                         wq, wo, wm, wig);

    // attention branch
    ln_fwd_k<<<M, 256, 0, stream>>>(x, ln1_w, ln1_b, h1);
    gemm_qkvt_k<<<768, 256, 0, stream>>>(h1, wq, qk_b, vt_b);
    attn_fwd_k<<<512, 256, 0, stream>>>(qk_b, vt_b, Ob);
    // attn_out: split-K=2 bf16 partials (512 blocks = 2/CU)
    gemm_btsplit_k<<<dim3(C / 128, M / 128, 2), 256, 0, stream>>>(
        Ob, wo, aoP, C, C, C / 2, M * C);
    // fused residual+LN2: x1 = x + p0 + p1 ; h2 = LN(x1)
    ln_resid_k<<<M, 256, 0, stream>>>(x, aoP, ln2_w, ln2_b, x1, h2, M * C);

    // MLP branch
    gemm256_k<2><<<dim3((2 * FF / 256) * (M / 256), 1, 1), 512, 0, stream>>>(
        h2, wig, ab, C, C, C, 2 * FF / 256, 8, FF, 0);
    gemm256_k<1><<<dim3((C / 256) * (M / 256), 1, 4), 512, 0, stream>>>(
        ab, wm, pscr, FF, FF, FF / 4, C / 256, 4, C, M * C);
    addreduce4_k<<<2048, 256, 0, stream>>>(x1, pscr, out, M * C / 4, M * C);
}